// Round 8
// baseline (168.519 us; speedup 1.0000x reference)
//
#include <hip/hip_runtime.h>
#include <hip/hip_bf16.h>

constexpr int Bn   = 32;
constexpr int CIN  = 128;
constexpr int Hh   = 56;
constexpr int Ww   = 56;
constexpr int HW   = Hh * Ww;      // 3136
constexpr int COUT = 128;
constexpr int En   = 8;

typedef __attribute__((ext_vector_type(8))) short bf16x8;   // 8 bf16 (4 VGPRs)
typedef __attribute__((ext_vector_type(4))) float f32x4;

struct GateInfo { int e0, e1; float w0, w1; };

// ---- xpad: [b][g=cin/32][row 0..57][col 0..57][4 quarters x 8 cin] bf16 ----
// quarter swizzle: physical quarter pq holds logical quarter (pq - (col>>1)) & 3
constexpr size_t ROWB = 58 * 64;            // 3712 B per padded row line
constexpr size_t PGB  = 58 * ROWB;          // 215,296 B per (b,g) plane
constexpr int TAPSTR  = COUT * CIN;         // 16384 elems per tap in wws

// ---- workspace layout (bytes) ----
constexpr size_t XP_OFF  = 0;
constexpr size_t XP_SZ   = (size_t)Bn * 4 * PGB;            // 27,557,888
constexpr size_t WW_OFF  = XP_OFF + XP_SZ;                  // bf16 combined W [b][tap][cout][cin]
constexpr size_t WW_SZ   = (size_t)Bn * 9 * COUT * CIN * 2; // 9,437,184
constexpr size_t HS_OFF  = WW_OFF + WW_SZ;                  // f32 per-(b,h,c) row sums
constexpr size_t HS_SZ   = (size_t)Bn * Hh * CIN * 4;
constexpr size_t GAP_OFF = HS_OFF + HS_SZ;
constexpr size_t GAP_SZ  = (size_t)Bn * CIN * 4;
constexpr size_t GI_OFF  = GAP_OFF + GAP_SZ;

__device__ inline void gload_lds16(const void* g, void* l) {
    __builtin_amdgcn_global_load_lds(
        (const __attribute__((address_space(1))) unsigned int*)g,
        (__attribute__((address_space(3))) unsigned int*)l, 16, 0, 0);
}

// ---------------- 1: NCHW f32 -> xpad bf16 (swizzled quarters), borders zeroed, row sums ----------------
// grid = Bn*Hh blocks (b,h), 256 threads
__global__ __launch_bounds__(256) void convert_kernel(const float* __restrict__ x,
        char* __restrict__ xpad, float* __restrict__ hsum) {
    __shared__ float lt[CIN * 57];   // [c][w], stride 57 (odd) for transpose reads
    int gid = blockIdx.x;
    int b = gid / Hh, h = gid % Hh;
    const float* xp = x + (size_t)b * CIN * HW + h * Ww;
    for (int u = threadIdx.x; u < CIN * Ww; u += 256) {
        int c = u / Ww, w = u % Ww;
        lt[c * 57 + w] = xp[(size_t)c * HW + w];
    }
    __syncthreads();
    char* dst = xpad + (size_t)b * 4 * PGB + (size_t)(h + 1) * ROWB;
    // 896 16B units: u = g*224 + w*4 + a; physical slot = (a + ((w+1)>>1)) & 3
    for (int u = threadIdx.x; u < 896; u += 256) {
        int g = u / 224, r = u % 224, w = r >> 2, a = r & 3;
        bf16x8 pk;
        #pragma unroll
        for (int j = 0; j < 8; j++) {
            __hip_bfloat16 t = __float2bfloat16(lt[(g * 32 + a * 8 + j) * 57 + w]);
            pk[j] = *reinterpret_cast<short*>(&t);
        }
        int pq = (a + ((w + 1) >> 1)) & 3;
        *(bf16x8*)(dst + (size_t)g * PGB + (size_t)(w + 1) * 64 + pq * 16) = pk;
    }
    // zero col borders (cols 0 and 57) for this row, all 4 g-planes
    if (threadIdx.x < 32) {
        int t = threadIdx.x, g = t >> 3, side = (t >> 2) & 1, q = t & 3;
        *(int4*)(xpad + (size_t)b * 4 * PGB + (size_t)g * PGB + (size_t)(h + 1) * ROWB
                 + (side ? 57 : 0) * 64 + q * 16) = (int4){0, 0, 0, 0};
    }
    // first/last h-blocks zero full rows 0 / 57
    if (h == 0 || h == 55) {
        int row = (h == 0) ? 0 : 57;
        char* base = xpad + (size_t)b * 4 * PGB + (size_t)row * ROWB;
        for (int u = threadIdx.x; u < 928; u += 256) {
            int g = u / 232, r = u % 232;
            *(int4*)(base + (size_t)g * PGB + (size_t)r * 16) = (int4){0, 0, 0, 0};
        }
    }
    if (threadIdx.x < CIN) {
        int c = threadIdx.x;
        float s = 0.f;
        #pragma unroll 8
        for (int w = 0; w < Ww; w++) s += lt[c * 57 + w];
        hsum[((size_t)b * Hh + h) * CIN + c] = s;
    }
}

// ---------------- 2: fused GAP finish + gate (logits -> top2 -> softmax) ----------------
// grid = Bn blocks (one per sample), 128 threads
__global__ __launch_bounds__(128) void gapgate_kernel(const float* __restrict__ hsum,
        const float* __restrict__ gate_w, const float* __restrict__ gate_b,
        float* __restrict__ wout, GateInfo* __restrict__ info) {
    __shared__ float gaps[CIN];
    __shared__ float lg[En];
    __shared__ GateInfo gsh;
    int b = blockIdx.x, tid = threadIdx.x;
    float s = 0.f;
    for (int h = 0; h < Hh; h++) s += hsum[((size_t)b * Hh + h) * CIN + tid];
    gaps[tid] = s * (1.f / (float)HW);
    __syncthreads();
    if (tid < En) {
        float t = gate_b[tid];
        #pragma unroll 8
        for (int c = 0; c < CIN; c++) t += gaps[c] * gate_w[tid * CIN + c];
        lg[tid] = t;
    }
    __syncthreads();
    if (tid == 0) {
        float v[En];
        #pragma unroll
        for (int k = 0; k < En; k++) v[k] = lg[k];
        int i0 = 0; float m0 = v[0];
        #pragma unroll
        for (int k = 1; k < En; k++) if (v[k] > m0) { m0 = v[k]; i0 = k; }
        int i1 = -1; float m1 = -1e30f;
        #pragma unroll
        for (int k = 0; k < En; k++) if (k != i0 && v[k] > m1) { m1 = v[k]; i1 = k; }
        float ex = expf(m1 - m0);
        float den = 1.f + ex;
        GateInfo t; t.e0 = i0; t.e1 = i1; t.w0 = 1.f / den; t.w1 = ex / den;
        gsh = t; info[b] = t;
    }
    __syncthreads();
    if (tid < En) {
        GateInfo t = gsh;
        wout[b * En + tid] = (tid == t.e0) ? t.w0 : (tid == t.e1) ? t.w1 : 0.f;
    }
}

// ---------------- 3: combined weights -> bf16 [b][tap][cout][cin] ----------------
// grid = Bn*8 blocks (b, cout-group of 16), 256 threads
__global__ __launch_bounds__(256) void wcomb_kernel(const float* __restrict__ cw,
        const GateInfo* __restrict__ info, __hip_bfloat16* __restrict__ wws) {
    __shared__ __hip_bfloat16 wl[16 * 1152];       // [co][cin][tap]
    int b = blockIdx.x >> 3, cg = blockIdx.x & 7;
    GateInfo gi = info[b];
    const float* p0 = cw + (size_t)gi.e0 * COUT * CIN * 9 + (size_t)cg * 16 * 1152;
    const float* p1 = cw + (size_t)gi.e1 * COUT * CIN * 9 + (size_t)cg * 16 * 1152;
    for (int u = threadIdx.x; u < 16 * 1152; u += 256)
        wl[u] = __float2bfloat16(gi.w0 * p0[u] + gi.w1 * p1[u]);
    __syncthreads();
    __hip_bfloat16* wo = wws + (size_t)b * 9 * COUT * CIN + (size_t)cg * 16 * CIN;
    // vectorized scatter: u = t*256 + co*16 + a  -> 16B store of 8 cins
    for (int u = threadIdx.x; u < 2304; u += 256) {
        int t = u >> 8, rem = u & 255, co = rem >> 4, a = rem & 15;
        bf16x8 pk;
        #pragma unroll
        for (int j = 0; j < 8; j++)
            pk[j] = *reinterpret_cast<short*>(&wl[co * 1152 + (a * 8 + j) * 9 + t]);
        *(bf16x8*)(wo + (size_t)t * COUT * CIN + co * CIN + a * 8) = pk;
    }
}

// ---------------- 4: implicit-GEMM conv via MFMA ----------------
// 224 blocks = 8 XCD x (4 samples x 7 row-blocks of 8), 512 thr = 8 waves
// (2 cout-halves x 4 pixel-quarters).  Wave tile: M=64 (Mrep=4) x N=112.
// KEY FIX vs r7: no vmem ops inside the compute phase.  A-fragments go
// through a single-buffered LDS slab `als` (9 taps x 128 cout x 32 cin),
// reg-staged for the next chunk (issue loads at chunk start, ds_write after
// the end-of-compute barrier).  vmcnt's in-order retirement then never
// forces compute to drain the xs staging (which serialized r5-r7).
constexpr int ACH = 9 * COUT * 32 * 2;     // 73,728 B A slab
__global__ __launch_bounds__(512, 2) void conv_mfma(
        const char* __restrict__ xpad,
        const __hip_bfloat16* __restrict__ wws,
        float* __restrict__ out) {
    __shared__ char xs[2][37120];
    __shared__ char als[ACH];              // total LDS 147,968 B

    int bid = blockIdx.x;
    int xcd = bid & 7, k = bid >> 3;       // 28 blocks per XCD
    int b   = xcd * 4 + k / 7;
    int rb  = k % 7;
    int row0 = rb * 8;
    int tid = threadIdx.x, wave = tid >> 6, lane = tid & 63;
    int cb = wave >> 2, wq = wave & 3;
    int cout0 = cb * 64;
    int l15 = lane & 15, lk = lane >> 4;

    const char* src = xpad + (size_t)b * 4 * PGB + (size_t)row0 * ROWB;
    const __hip_bfloat16* wwb = wws + (size_t)b * 9 * TAPSTR;

    // B-read bases per Ntile: bA (quarter shift s), bB (s+1), bC = dc==1 select
    int bA[7], bB[7], bC[7];
    #pragma unroll
    for (int i = 0; i < 7; i++) {
        int p = wq * 112 + i * 16 + l15;   // pixel within the 448-span
        int r = p / 56, m = p % 56;
        int base = r * (int)ROWB + m * 64;
        bA[i] = base + ((lk + (m >> 1)) & 3) * 16;
        bB[i] = base + ((lk + (m >> 1) + 1) & 3) * 16;
        bC[i] = (m & 1) ? bB[i] : bA[i];
    }

    f32x4 acc[4][7];
    #pragma unroll
    for (int mt = 0; mt < 4; mt++)
        #pragma unroll
        for (int i = 0; i < 7; i++) acc[mt][i] = (f32x4){0.f, 0.f, 0.f, 0.f};

    // A unit n = tap*512 + cout*4 + lk  (16B each); thread owns n = kk*512+tid
    int4 areg[9];
    #pragma unroll
    for (int kk = 0; kk < 9; kk++) {
        int n = kk * 512 + tid;
        int tap = n >> 9, r = n & 511, co = r >> 2, lk8 = (r & 3) * 8;
        areg[kk] = *(const int4*)(wwb + (size_t)tap * TAPSTR + co * CIN + lk8);
    }
    // stage xs chunk 0 (2320 16B units)
    #pragma unroll
    for (int kk = 0; kk < 5; kk++) {
        int idx = kk * 512 + tid;
        if (idx < 2320) gload_lds16(src + (size_t)idx * 16, &xs[0][idx * 16]);
    }
    // write A(0) (waits A-loads; xs loads younger, keep flying)
    #pragma unroll
    for (int kk = 0; kk < 9; kk++)
        *(int4*)(als + ((size_t)(kk * 512 + tid)) * 16) = areg[kk];
    __syncthreads();

    for (int g = 0; g < 4; ++g) {
        if (g < 3) {                       // issue next chunk's loads; fly under MFMA
            const char* s2 = src + (size_t)(g + 1) * PGB;
            #pragma unroll
            for (int kk = 0; kk < 5; kk++) {
                int idx = kk * 512 + tid;
                if (idx < 2320) gload_lds16(s2 + (size_t)idx * 16, &xs[(g + 1) & 1][idx * 16]);
            }
            const int c1 = (g + 1) * 32;
            #pragma unroll
            for (int kk = 0; kk < 9; kk++) {
                int n = kk * 512 + tid;
                int tap = n >> 9, r = n & 511, co = r >> 2, lk8 = (r & 3) * 8;
                areg[kk] = *(const int4*)(wwb + (size_t)tap * TAPSTR + co * CIN + c1 + lk8);
            }
        }
        const char* xb = xs[g & 1];
        #pragma unroll
        for (int t = 0; t < 9; t++) {
            bf16x8 a[4];
            #pragma unroll
            for (int mt = 0; mt < 4; mt++)
                a[mt] = *(const bf16x8*)(als + t * 8192 + (cout0 + mt * 16 + l15) * 64 + lk * 16);
            const int dr = t / 3, dc = t % 3;
            const int imm = dr * (int)ROWB + dc * 64;
            #pragma unroll
            for (int i = 0; i < 7; i++) {
                int boff = (dc == 0) ? bA[i] : (dc == 1) ? bC[i] : bB[i];
                bf16x8 bv = *(const bf16x8*)(xb + boff + imm);
                #pragma unroll
                for (int mt = 0; mt < 4; mt++)
                    acc[mt][i] = __builtin_amdgcn_mfma_f32_16x16x32_bf16(
                        a[mt], bv, acc[mt][i], 0, 0, 0);
            }
        }
        __syncthreads();                   // all waves done reading als + xs[g&1]; drains vmem
        if (g < 3) {
            #pragma unroll
            for (int kk = 0; kk < 9; kk++)
                *(int4*)(als + ((size_t)(kk * 512 + tid)) * 16) = areg[kk];
        }
        __syncthreads();                   // als(g+1) visible to all waves
    }

    // epilogue: C/D layout col=lane&15 (pixel), row=(lane>>4)*4+j (cout)
    float* outb = out + (size_t)b * COUT * HW + row0 * 56;
    #pragma unroll
    for (int mt = 0; mt < 4; mt++) {
        int cbase = cout0 + mt * 16 + lk * 4;
        #pragma unroll
        for (int i = 0; i < 7; i++) {
            int pp = wq * 112 + i * 16 + l15;
            #pragma unroll
            for (int j = 0; j < 4; j++)
                outb[(size_t)(cbase + j) * HW + pp] = acc[mt][i][j];
        }
    }
}

// ---------------- launch ----------------
extern "C" void kernel_launch(void* const* d_in, const int* in_sizes, int n_in,
                              void* d_out, int out_size, void* d_ws, size_t ws_size,
                              hipStream_t stream) {
    const float* x  = (const float*)d_in[0];
    const float* cw = (const float*)d_in[1];
    const float* gw = (const float*)d_in[2];
    const float* gb = (const float*)d_in[3];

    float* out = (float*)d_out;
    char* ws = (char*)d_ws;
    char* xpad           = ws + XP_OFF;
    __hip_bfloat16* wws  = (__hip_bfloat16*)(ws + WW_OFF);
    float* hsum          = (float*)(ws + HS_OFF);
    GateInfo* info       = (GateInfo*)(ws + GI_OFF);
    float* wout = out + (size_t)Bn * COUT * HW;

    convert_kernel<<<Bn * Hh, 256, 0, stream>>>(x, xpad, hsum);
    gapgate_kernel<<<Bn,      128, 0, stream>>>(hsum, gw, gb, wout, info);
    wcomb_kernel  <<<Bn * 8,  256, 0, stream>>>(cw, info, wws);
    conv_mfma     <<<224,     512, 0, stream>>>(xpad, wws, out);
}